// Round 9
// baseline (197.432 us; speedup 1.0000x reference)
//
#include <hip/hip_runtime.h>

// MHA: B=2, H=8, S=4096, Hd=64, D=512. Inputs fp32 (dict order), output fp32.
// Internal compute bf16 MFMA.
//   prep:   one-shot fp32->bf16 convert of x and Wq/Wk/Wv/Wo into ws
//           (enables global_load_lds DMA staging in the GEMMs).
//   proj:   m97-style GEMM: linear [128][32] LDS tiles via
//           global_load_lds width=16, BK=32, 2 barriers/iter.
//           Grid (64,4,3) x 256 thr. z=0 Q(scaled), z=1 K, z=2 Vt(transposed).
//   attn:   R8-verified (frozen): flash w/o online max, 32x32x16 MFMA,
//           swapped QK^T, in-register softmax, WQ=64, 2 key-halves,
//           XCD swizzle. Grid (16,16) x 512 thr.
//   out:    m97-style GEMM, O(bf16) x Wo^T + bo -> fp32.
// ws: Q/O + K + Vt + xb + Wb = 35.7 MB.

typedef unsigned short ushortT;
typedef __attribute__((ext_vector_type(8))) short short8;   // 8 bf16 (MFMA A/B frag)
typedef __attribute__((ext_vector_type(4))) float f32x4;    // 16x16 MFMA C/D frag
typedef __attribute__((ext_vector_type(16))) float f32x16;  // 32x32 MFMA C/D frag
typedef __attribute__((ext_vector_type(4))) unsigned int uint4v;
typedef __attribute__((ext_vector_type(2))) unsigned int uint2v;

__device__ __forceinline__ ushortT f2bf(float f) {
    unsigned int u = __builtin_bit_cast(unsigned int, f);
    u += 0x7FFFu + ((u >> 16) & 1u);   // round-to-nearest-even
    return (ushortT)(u >> 16);
}

// pack 2 fp32 -> 2 bf16 in one dword (HW RNE)
__device__ __forceinline__ unsigned int cvtpk(float lo, float hi) {
    unsigned int d;
    asm("v_cvt_pk_bf16_f32 %0, %1, %2" : "=v"(d) : "v"(lo), "v"(hi));
    return d;
}

// 8 fp32 -> 8 bf16 packed in a uint4v (4 cvt_pk instrs)
__device__ __forceinline__ uint4v pk8(f32x4 a0, f32x4 a1) {
    uint4v r = { cvtpk(a0[0], a0[1]), cvtpk(a0[2], a0[3]),
                 cvtpk(a1[0], a1[1]), cvtpk(a1[2], a1[3]) };
    return r;
}

// a <- {a.lo32lanes, b.lo32lanes}; b <- {a.hi32lanes, b.hi32lanes}
__device__ __forceinline__ void plswap(unsigned int &a, unsigned int &b) {
    uint2v r = __builtin_amdgcn_permlane32_swap(a, b, false, false);
    a = r[0]; b = r[1];
}

// async global->LDS DMA, 16B/lane. LDS dst is WAVE-UNIFORM base; HW writes
// lane l at base + l*16 bytes. Global src is per-lane.
__device__ __forceinline__ void gload16(const ushortT* g, ushortT* l) {
    __builtin_amdgcn_global_load_lds(
        (const __attribute__((address_space(1))) void*)g,
        (__attribute__((address_space(3))) void*)l, 16, 0, 0);
}

#define ALDK 72   // LDS row stride (shorts), attn tiles

// ---------------------------------------------------------------------------
// prep: convert x (8192x512) and Wq/Wk/Wv/Wo (512x512 each) fp32 -> bf16.
// Grid 2560 x 256: blocks [0,2048) -> x; [2048,2560) -> W's (128 each).
// ---------------------------------------------------------------------------
__global__ __launch_bounds__(256) void prep(
    const float* __restrict__ x,  const float* __restrict__ Wq,
    const float* __restrict__ Wk, const float* __restrict__ Wv,
    const float* __restrict__ Wo,
    ushortT* __restrict__ xb, ushortT* __restrict__ wb)
{
    const int bid = blockIdx.x, t = threadIdx.x;
    const float* src; ushortT* dst; size_t base;
    if (bid < 2048) { src = x; dst = xb; base = (size_t)bid * 2048; }
    else {
        int r = bid - 2048, wsel = r >> 7, rb = r & 127;
        src = (wsel == 0) ? Wq : (wsel == 1) ? Wk : (wsel == 2) ? Wv : Wo;
        dst = wb + (size_t)wsel * 262144;
        base = (size_t)rb * 2048;
    }
    const size_t off = base + (size_t)t * 8;
    f32x4 a0 = *(const f32x4*)(src + off);
    f32x4 a1 = *(const f32x4*)(src + off + 4);
    *(uint4v*)(dst + off) = pk8(a0, a1);
}

// ---------------------------------------------------------------------------
// QKV projection, m97-style. Grid (64,4,3) x 256 thr / 4 waves.
// 128x128 tile, BK=32. Linear [128][32] LDS tiles; wave w DMAs its two
// 16-row slabs of A and B per K-step (lane l -> row l>>2, col (l&3)*8 within
// the slab == HW's base + l*16B). 2 barriers/iter (vmcnt drained at barrier).
// z=0 -> Q (scaled), z=1 -> K, z=2 -> Vt (transposed epilogue).
// ---------------------------------------------------------------------------
__global__ __launch_bounds__(256) void proj_qkv(
    const ushortT* __restrict__ xb, const ushortT* __restrict__ wb,
    const float* __restrict__ bq, const float* __restrict__ bk,
    const float* __restrict__ bv,
    ushortT* __restrict__ Qw, ushortT* __restrict__ Kw,
    ushortT* __restrict__ Vtw, float qscale)
{
    __shared__ __align__(16) ushortT As[128 * 32];
    __shared__ __align__(16) ushortT Bs[128 * 32];
    const int t = threadIdx.x;
    const int w = t >> 6, lane = t & 63;
    const int quad = lane >> 4, l15 = lane & 15;
    const int z = blockIdx.z;
    const int arow0 = blockIdx.x * 128;   // seq rows (x side)
    const int brow0 = blockIdx.y * 128;   // out channels (W side)
    const int wm = (w >> 1) * 64, wn = (w & 1) * 64;

    const ushortT* Wz = wb + (size_t)z * 262144;
    const float* bias = (z == 0) ? bq : (z == 1) ? bk : bv;

    // DMA src coords: wave w covers rows [w*32, w*32+32) as two 16-row slabs
    const int srow = lane >> 2;          // 0..15 within slab
    const int scol = (lane & 3) * 8;     // shorts
    ushortT* Ad0 = As + (w * 2 + 0) * 512;   // 16 rows x 32 shorts per slab
    ushortT* Ad1 = As + (w * 2 + 1) * 512;
    ushortT* Bd0 = Bs + (w * 2 + 0) * 512;
    ushortT* Bd1 = Bs + (w * 2 + 1) * 512;

    f32x4 acc[4][4] = {};

    for (int k0 = 0; k0 < 512; k0 += 32) {
        gload16(xb + (size_t)(arow0 + w * 32 +      srow) * 512 + k0 + scol, Ad0);
        gload16(xb + (size_t)(arow0 + w * 32 + 16 + srow) * 512 + k0 + scol, Ad1);
        gload16(Wz + (size_t)(brow0 + w * 32 +      srow) * 512 + k0 + scol, Bd0);
        gload16(Wz + (size_t)(brow0 + w * 32 + 16 + srow) * 512 + k0 + scol, Bd1);
        __syncthreads();   // drains vmcnt -> LDS tile ready

        short8 af[4], bfr[4];
#pragma unroll
        for (int i = 0; i < 4; i++)
            af[i] = *(const short8*)(As + (wm + i * 16 + l15) * 32 + quad * 8);
#pragma unroll
        for (int i = 0; i < 4; i++)
            bfr[i] = *(const short8*)(Bs + (wn + i * 16 + l15) * 32 + quad * 8);
#pragma unroll
        for (int mi = 0; mi < 4; mi++)
#pragma unroll
            for (int ni = 0; ni < 4; ni++)
                acc[mi][ni] = __builtin_amdgcn_mfma_f32_16x16x32_bf16(
                    af[mi], bfr[ni], acc[mi][ni], 0, 0, 0);
        __syncthreads();   // all reads done before next iter's DMA
    }

    if (z < 2) {
        ushortT* Y = (z == 0) ? Qw : Kw;
        const float sc = (z == 0) ? qscale : 1.0f;
#pragma unroll
        for (int ni = 0; ni < 4; ni++) {
            int col = brow0 + wn + ni * 16 + l15;
            float bv_ = bias[col];
#pragma unroll
            for (int mi = 0; mi < 4; mi++)
#pragma unroll
                for (int r = 0; r < 4; r++) {
                    int row = arow0 + wm + mi * 16 + quad * 4 + r;
                    Y[(size_t)row * 512 + col] = f2bf((acc[mi][ni][r] + bv_) * sc);
                }
        }
    } else {
        // V transposed -> Vt[b][ch][seq]; ch = col side, seq = row side.
        const int bidx = arow0 >> 12;
        const int s0 = (arow0 & 4095) + wm;
#pragma unroll
        for (int ni = 0; ni < 4; ni++) {
            int ch = brow0 + wn + ni * 16 + l15;
            float bv_ = bias[ch];
            ushortT* vrow = Vtw + (size_t)bidx * 2097152 + (size_t)ch * 4096;
#pragma unroll
            for (int mi = 0; mi < 4; mi++) {
                int s = s0 + mi * 16 + quad * 4;
                unsigned int u0 = cvtpk(acc[mi][ni][0] + bv_, acc[mi][ni][1] + bv_);
                unsigned int u1 = cvtpk(acc[mi][ni][2] + bv_, acc[mi][ni][3] + bv_);
                uint2v st2 = { u0, u1 };
                *(uint2v*)(vrow + s) = st2;
            }
        }
    }
}

// ---------------------------------------------------------------------------
// Final projection, m97-style: out[M][512] = O[M][512](bf16) * Wo^T + bo.
// Grid (64,4) x 256 thr. Same DMA staging as proj_qkv.
// ---------------------------------------------------------------------------
__global__ __launch_bounds__(256) void gemm_out(
    const ushortT* __restrict__ X, const ushortT* __restrict__ Wob,
    const float* __restrict__ bias, float* __restrict__ Y)
{
    __shared__ __align__(16) ushortT As[128 * 32];
    __shared__ __align__(16) ushortT Bs[128 * 32];
    const int t = threadIdx.x;
    const int w = t >> 6, lane = t & 63;
    const int quad = lane >> 4, l15 = lane & 15;
    const int bm = blockIdx.x * 128, bn = blockIdx.y * 128;
    const int wm = (w >> 1) * 64, wn = (w & 1) * 64;

    const int srow = lane >> 2;
    const int scol = (lane & 3) * 8;
    ushortT* Ad0 = As + (w * 2 + 0) * 512;
    ushortT* Ad1 = As + (w * 2 + 1) * 512;
    ushortT* Bd0 = Bs + (w * 2 + 0) * 512;
    ushortT* Bd1 = Bs + (w * 2 + 1) * 512;

    f32x4 acc[4][4] = {};

    for (int k0 = 0; k0 < 512; k0 += 32) {
        gload16(X   + (size_t)(bm + w * 32 +      srow) * 512 + k0 + scol, Ad0);
        gload16(X   + (size_t)(bm + w * 32 + 16 + srow) * 512 + k0 + scol, Ad1);
        gload16(Wob + (size_t)(bn + w * 32 +      srow) * 512 + k0 + scol, Bd0);
        gload16(Wob + (size_t)(bn + w * 32 + 16 + srow) * 512 + k0 + scol, Bd1);
        __syncthreads();

        short8 af[4], bfr[4];
#pragma unroll
        for (int i = 0; i < 4; i++)
            af[i] = *(const short8*)(As + (wm + i * 16 + l15) * 32 + quad * 8);
#pragma unroll
        for (int i = 0; i < 4; i++)
            bfr[i] = *(const short8*)(Bs + (wn + i * 16 + l15) * 32 + quad * 8);
#pragma unroll
        for (int mi = 0; mi < 4; mi++)
#pragma unroll
            for (int ni = 0; ni < 4; ni++)
                acc[mi][ni] = __builtin_amdgcn_mfma_f32_16x16x32_bf16(
                    af[mi], bfr[ni], acc[mi][ni], 0, 0, 0);
        __syncthreads();
    }

#pragma unroll
    for (int ni = 0; ni < 4; ni++) {
        int col = bn + wn + ni * 16 + l15;
        float bv = bias[col];
#pragma unroll
        for (int mi = 0; mi < 4; mi++)
#pragma unroll
            for (int r = 0; r < 4; r++) {
                int row = bm + wm + mi * 16 + quad * 4 + r;
                Y[(size_t)row * 512 + col] = acc[mi][ni][r] + bv;
            }
    }
}

// ---------------------------------------------------------------------------
// p = exp2(s) for a 32x32 S^T-tile; accumulate per-lane row-sum; assemble
// the two PV B-frags (16 k-slots each) via cvt_pk + permlane32_swap.
// ---------------------------------------------------------------------------
__device__ __forceinline__ void softmax_pack(const f32x16 &sacc, float &lp,
                                             uint4v &B0, uint4v &B1)
{
    float p[16];
#pragma unroll
    for (int r = 0; r < 16; r++) {
        p[r] = __builtin_amdgcn_exp2f(sacc[r]);
        lp += p[r];
    }
    unsigned int c00 = cvtpk(p[0],  p[1]),  c01 = cvtpk(p[2],  p[3]);
    unsigned int c10 = cvtpk(p[4],  p[5]),  c11 = cvtpk(p[6],  p[7]);
    unsigned int c20 = cvtpk(p[8],  p[9]),  c21 = cvtpk(p[10], p[11]);
    unsigned int c30 = cvtpk(p[12], p[13]), c31 = cvtpk(p[14], p[15]);
    plswap(c00, c10);   // -> B0.d0, B0.d2   (k-slots 0..15)
    plswap(c01, c11);   // -> B0.d1, B0.d3
    plswap(c20, c30);   // -> B1.d0, B1.d2   (k-slots 16..31)
    plswap(c21, c31);   // -> B1.d1, B1.d3
    B0 = uint4v{ c00, c01, c10, c11 };
    B1 = uint4v{ c20, c21, c30, c31 };
}

// ---------------------------------------------------------------------------
// Flash attention — R8-verified (frozen). XCD-aware swizzle; WQ=64 per wave;
// 8 waves = 2 key-halves x 4 q-waves; double-buffered K/V LDS, ONE barrier
// per k-tile; fp32 LDS combine. Grid (16,16) x 512 thr. Q/O alias.
// ---------------------------------------------------------------------------
__global__ __launch_bounds__(512, 2) void attn(
    const ushortT* Q, const ushortT* __restrict__ K,
    const ushortT* __restrict__ Vt, ushortT* O)
{
    __shared__ __align__(16) ushortT SM[2][2][2][64 * ALDK];   // [K/V][half][buf]

    const int t = threadIdx.x;
    const int w = t >> 6, lane = t & 63;
    const int half = w >> 2, qw = w & 3;
    const int l31 = lane & 31, hh = lane >> 5;

    // XCD-aware swizzle (pure index permutation)
    const int j = blockIdx.x + (blockIdx.y << 4);
    const int qt = (j >> 3) & 15;
    const int bh = ((j & 7) << 1) | (j >> 7);

    const int b = bh >> 3, h = bh & 7;
    const size_t qbase = (size_t)b * 4096 + qt * 256 + qw * 64;

    short8 qf[2][4];
#pragma unroll
    for (int qg = 0; qg < 2; qg++) {
        const ushortT* qp = Q + (qbase + qg * 32 + l31) * 512 + h * 64 + hh * 8;
#pragma unroll
        for (int dk = 0; dk < 4; dk++)
            qf[qg][dk] = *(const short8*)(qp + dk * 16);
    }

    f32x16 oacc[2][2] = {};   // [qg][dt] unnormalized O^T[d][q]
    float lpart[2] = {};      // per-lane row-sum partial per qg

    const int kofs = half * 2048;
    const ushortT* Kbase = K + ((size_t)b * 4096 + kofs) * 512 + h * 64;
    const ushortT* Vbase = Vt + (size_t)b * 2097152 + (size_t)h * 64 * 4096 + kofs;

    const int th = t & 255;
    const int srow = th >> 3, scol = (th & 7) * 8;
    uint4v kg[2], vg[2];

#pragma unroll
    for (int i = 0; i < 2; i++) {
        kg[i] = *(const uint4v*)(Kbase + (size_t)(srow + 32 * i) * 512 + scol);
        vg[i] = *(const uint4v*)(Vbase + (size_t)(srow + 32 * i) * 4096 + scol);
    }
#pragma unroll
    for (int i = 0; i < 2; i++) {
        *(uint4v*)(SM[0][half][0] + (srow + 32 * i) * ALDK + scol) = kg[i];
        *(uint4v*)(SM[1][half][0] + (srow + 32 * i) * ALDK + scol) = vg[i];
    }
    __syncthreads();

    for (int kt = 0; kt < 32; kt++) {
        const int cur = kt & 1;

        if (kt < 31) {
            const int kb = (kt + 1) * 64;
#pragma unroll
            for (int i = 0; i < 2; i++) {
                kg[i] = *(const uint4v*)(Kbase + (size_t)(kb + srow + 32 * i) * 512 + scol);
                vg[i] = *(const uint4v*)(Vbase + (size_t)(srow + 32 * i) * 4096 + kb + scol);
            }
        }

        const ushortT* Kt  = SM[0][half][cur];
        const ushortT* Vtl = SM[1][half][cur];

#pragma unroll
        for (int st = 0; st < 2; st++) {
            short8 kf[4];
#pragma unroll
            for (int dk = 0; dk < 4; dk++)
                kf[dk] = *(const short8*)(Kt + (st * 32 + l31) * ALDK + dk * 16 + hh * 8);
            f32x16 s0 = {}, s1 = {};
#pragma unroll
            for (int dk = 0; dk < 4; dk++) {
                s0 = __builtin_amdgcn_mfma_f32_32x32x16_bf16(kf[dk], qf[0][dk], s0, 0, 0, 0);
                s1 = __builtin_amdgcn_mfma_f32_32x32x16_bf16(kf[dk], qf[1][dk], s1, 0, 0, 0);
            }

            uint4v B00, B01, B10, B11;
            softmax_pack(s0, lpart[0], B00, B01);
            softmax_pack(s1, lpart[1], B10, B11);
            short8 p00 = __builtin_bit_cast(short8, B00);
            short8 p01 = __builtin_bit_cast(short8, B01);
            short8 p10 = __builtin_bit_cast(short8, B10);
            short8 p11 = __builtin_bit_cast(short8, B11);

#pragma unroll
            for (int dt = 0; dt < 2; dt++) {
                short8 vf0 = *(const short8*)(Vtl + (dt * 32 + l31) * ALDK + st * 32 + hh * 8);
                short8 vf1 = *(const short8*)(Vtl + (dt * 32 + l31) * ALDK + st * 32 + 16 + hh * 8);
                oacc[0][dt] = __builtin_amdgcn_mfma_f32_32x32x16_bf16(vf0, p00, oacc[0][dt], 0, 0, 0);
                oacc[0][dt] = __builtin_amdgcn_mfma_f32_32x32x16_bf16(vf1, p01, oacc[0][dt], 0, 0, 0);
                oacc[1][dt] = __builtin_amdgcn_mfma_f32_32x32x16_bf16(vf0, p10, oacc[1][dt], 0, 0, 0);
                oacc[1][dt] = __builtin_amdgcn_mfma_f32_32x32x16_bf16(vf1, p11, oacc[1][dt], 0, 0, 0);
            }
        }

        if (kt < 31) {
            const int nb = cur ^ 1;
#pragma unroll
            for (int i = 0; i < 2; i++) {
                *(uint4v*)(SM[0][half][nb] + (srow + 32 * i) * ALDK + scol) = kg[i];
                *(uint4v*)(SM[1][half][nb] + (srow + 32 * i) * ALDK + scol) = vg[i];
            }
        }
        __syncthreads();
    }

    float* scratch = (float*)&SM[0][0][0][0];
    float* prow = scratch + (size_t)(qw * 64 + lane) * 68;

    if (half == 1) {
#pragma unroll
        for (int qg = 0; qg < 2; qg++)
#pragma unroll
            for (int dt = 0; dt < 2; dt++)
#pragma unroll
                for (int m = 0; m < 4; m++) {
                    f32x4 v4 = { oacc[qg][dt][4 * m + 0], oacc[qg][dt][4 * m + 1],
                                 oacc[qg][dt][4 * m + 2], oacc[qg][dt][4 * m + 3] };
                    *(f32x4*)(prow + qg * 32 + dt * 16 + m * 4) = v4;
                }
        prow[64] = lpart[0];
        prow[65] = lpart[1];
    }
    __syncthreads();

    if (half == 0) {
#pragma unroll
        for (int qg = 0; qg < 2; qg++) {
            float sum = lpart[qg] + prow[64 + qg];
            float l = sum + __shfl_xor(sum, 32);
            float rl = 1.0f / l;

            ushortT* orow = O + (qbase + qg * 32 + l31) * 512 + h * 64 + hh * 4;
#pragma unroll
            for (int dt = 0; dt < 2; dt++)
#pragma unroll
                for (int m = 0; m < 4; m++) {
                    f32x4 v4 = *(const f32x4*)(prow + qg * 32 + dt * 16 + m * 4);
                    unsigned int u0 = cvtpk((oacc[qg][dt][4 * m + 0] + v4[0]) * rl,
                                            (oacc[qg][dt][4 * m + 1] + v4[1]) * rl);
                    unsigned int u1 = cvtpk((oacc[qg][dt][4 * m + 2] + v4[2]) * rl,
                                            (oacc[qg][dt][4 * m + 3] + v4[3]) * rl);
                    uint2v st2 = { u0, u1 };
                    *(uint2v*)(orow + dt * 32 + m * 8) = st2;
                }
        }
    }
}

// ---------------------------------------------------------------------------
extern "C" void kernel_launch(void* const* d_in, const int* in_sizes, int n_in,
                              void* d_out, int out_size, void* d_ws, size_t ws_size,
                              hipStream_t stream)
{
    const float* x  = (const float*)d_in[0];
    const float* Wq = (const float*)d_in[1];
    const float* bq = (const float*)d_in[2];
    const float* Wk = (const float*)d_in[3];
    const float* bk = (const float*)d_in[4];
    const float* Wv = (const float*)d_in[5];
    const float* bv = (const float*)d_in[6];
    const float* Wo = (const float*)d_in[7];
    const float* bo = (const float*)d_in[8];

    ushortT* ws  = (ushortT*)d_ws;
    ushortT* Qw  = ws;                    // 8192*512 bf16 (O in place)
    ushortT* Kw  = ws + 4194304;
    ushortT* Vtw = ws + 8388608;          // 2*512*4096 bf16
    ushortT* xb  = ws + 12582912;         // 8192*512 bf16
    ushortT* wbf = ws + 16777216;         // 4 x 512*512 bf16 (q,k,v,o)

    const float qscale = 0.125f * 1.44269504089f;   // 1/sqrt(64) * log2(e)

    prep<<<dim3(2560), 256, 0, stream>>>(x, Wq, Wk, Wv, Wo, xb, wbf);
    proj_qkv<<<dim3(64, 4, 3), 256, 0, stream>>>(
        xb, wbf, bq, bk, bv, Qw, Kw, Vtw, qscale);
    attn<<<dim3(16, 16), 512, 0, stream>>>(Qw, Kw, Vtw, Qw);
    gemm_out<<<dim3(64, 4), 256, 0, stream>>>(Qw, wbf + 786432, bo, (float*)d_out);
}

// Round 10
// 195.831 us; speedup vs baseline: 1.0082x; 1.0082x over previous
//
#include <hip/hip_runtime.h>

// MHA: B=2, H=8, S=4096, Hd=64, D=512. Inputs fp32 (dict order), output fp32.
// Internal compute bf16 MFMA.
//   prep:   one-shot fp32->bf16 convert of x and Wq/Wk/Wv/Wo into ws.
//   proj:   2-PHASE GEMM (T3-minimum): double-buffered [2][128][32] LDS via
//           global_load_lds w=16; per iter {DMA next -> buf^1, ds_read buf,
//           16 MFMA, ONE barrier}. Grid (64,4,3) x 256 thr, 4 blocks/CU.
//   attn:   R8-verified (frozen): flash w/o online max, 32x32x16 MFMA,
//           swapped QK^T, in-register softmax, WQ=64, 2 key-halves,
//           XCD swizzle. Grid (16,16) x 512 thr.
//   out:    2-phase GEMM, O(bf16) x Wo^T + bo -> fp32.
// ws: Q/O + K + Vt + xb + Wb = 35.7 MB.

typedef unsigned short ushortT;
typedef __attribute__((ext_vector_type(8))) short short8;   // 8 bf16 (MFMA A/B frag)
typedef __attribute__((ext_vector_type(4))) float f32x4;    // 16x16 MFMA C/D frag
typedef __attribute__((ext_vector_type(16))) float f32x16;  // 32x32 MFMA C/D frag
typedef __attribute__((ext_vector_type(4))) unsigned int uint4v;
typedef __attribute__((ext_vector_type(2))) unsigned int uint2v;

__device__ __forceinline__ ushortT f2bf(float f) {
    unsigned int u = __builtin_bit_cast(unsigned int, f);
    u += 0x7FFFu + ((u >> 16) & 1u);   // round-to-nearest-even
    return (ushortT)(u >> 16);
}

// pack 2 fp32 -> 2 bf16 in one dword (HW RNE)
__device__ __forceinline__ unsigned int cvtpk(float lo, float hi) {
    unsigned int d;
    asm("v_cvt_pk_bf16_f32 %0, %1, %2" : "=v"(d) : "v"(lo), "v"(hi));
    return d;
}

// 8 fp32 -> 8 bf16 packed in a uint4v (4 cvt_pk instrs)
__device__ __forceinline__ uint4v pk8(f32x4 a0, f32x4 a1) {
    uint4v r = { cvtpk(a0[0], a0[1]), cvtpk(a0[2], a0[3]),
                 cvtpk(a1[0], a1[1]), cvtpk(a1[2], a1[3]) };
    return r;
}

// a <- {a.lo32lanes, b.lo32lanes}; b <- {a.hi32lanes, b.hi32lanes}
__device__ __forceinline__ void plswap(unsigned int &a, unsigned int &b) {
    uint2v r = __builtin_amdgcn_permlane32_swap(a, b, false, false);
    a = r[0]; b = r[1];
}

// async global->LDS DMA, 16B/lane. LDS dst is WAVE-UNIFORM base; HW writes
// lane l at base + l*16 bytes. Global src is per-lane.
__device__ __forceinline__ void gload16(const ushortT* g, ushortT* l) {
    __builtin_amdgcn_global_load_lds(
        (const __attribute__((address_space(1))) void*)g,
        (__attribute__((address_space(3))) void*)l, 16, 0, 0);
}

#define ALDK 72   // LDS row stride (shorts), attn tiles

// ---------------------------------------------------------------------------
// prep: convert x (8192x512) and Wq/Wk/Wv/Wo (512x512 each) fp32 -> bf16.
// Grid 2560 x 256: blocks [0,2048) -> x; [2048,2560) -> W's (128 each).
// ---------------------------------------------------------------------------
__global__ __launch_bounds__(256) void prep(
    const float* __restrict__ x,  const float* __restrict__ Wq,
    const float* __restrict__ Wk, const float* __restrict__ Wv,
    const float* __restrict__ Wo,
    ushortT* __restrict__ xb, ushortT* __restrict__ wb)
{
    const int bid = blockIdx.x, t = threadIdx.x;
    const float* src; ushortT* dst; size_t base;
    if (bid < 2048) { src = x; dst = xb; base = (size_t)bid * 2048; }
    else {
        int r = bid - 2048, wsel = r >> 7, rb = r & 127;
        src = (wsel == 0) ? Wq : (wsel == 1) ? Wk : (wsel == 2) ? Wv : Wo;
        dst = wb + (size_t)wsel * 262144;
        base = (size_t)rb * 2048;
    }
    const size_t off = base + (size_t)t * 8;
    f32x4 a0 = *(const f32x4*)(src + off);
    f32x4 a1 = *(const f32x4*)(src + off + 4);
    *(uint4v*)(dst + off) = pk8(a0, a1);
}

// ---------------------------------------------------------------------------
// QKV projection, 2-phase dbuf. Grid (64,4,3) x 256 thr / 4 waves.
// 128x128 tile, BK=32. Per iter: issue DMA for k0+32 into buf^1 FIRST,
// then ds_read buf + 16 MFMA, then ONE barrier (vmcnt drain lands after
// the MFMA phase covered the load latency).
// z=0 -> Q (scaled), z=1 -> K, z=2 -> Vt (transposed epilogue).
// ---------------------------------------------------------------------------
__global__ __launch_bounds__(256) void proj_qkv(
    const ushortT* __restrict__ xb, const ushortT* __restrict__ wb,
    const float* __restrict__ bq, const float* __restrict__ bk,
    const float* __restrict__ bv,
    ushortT* __restrict__ Qw, ushortT* __restrict__ Kw,
    ushortT* __restrict__ Vtw, float qscale)
{
    __shared__ __align__(16) ushortT As[2][128 * 32];
    __shared__ __align__(16) ushortT Bs[2][128 * 32];
    const int t = threadIdx.x;
    const int w = t >> 6, lane = t & 63;
    const int quad = lane >> 4, l15 = lane & 15;
    const int z = blockIdx.z;
    const int arow0 = blockIdx.x * 128;   // seq rows (x side)
    const int brow0 = blockIdx.y * 128;   // out channels (W side)
    const int wm = (w >> 1) * 64, wn = (w & 1) * 64;

    const ushortT* Wz = wb + (size_t)z * 262144;
    const float* bias = (z == 0) ? bq : (z == 1) ? bk : bv;

    // DMA coords: wave w covers rows [w*32, +32) as two 16-row slabs;
    // lane l -> row l>>2, col (l&3)*8 within slab (== base + l*16B).
    const int srow = lane >> 2;
    const int scol = (lane & 3) * 8;
    const size_t asrc = (size_t)(arow0 + w * 32 + srow) * 512 + scol;
    const size_t bsrc = (size_t)(brow0 + w * 32 + srow) * 512 + scol;

    f32x4 acc[4][4] = {};

    // prologue: tile 0 -> buf 0
    gload16(xb + asrc,        As[0] + (w * 2 + 0) * 512);
    gload16(xb + asrc + 8192, As[0] + (w * 2 + 1) * 512);   // +16 rows
    gload16(Wz + bsrc,        Bs[0] + (w * 2 + 0) * 512);
    gload16(Wz + bsrc + 8192, Bs[0] + (w * 2 + 1) * 512);
    __syncthreads();

    int cur = 0;
    for (int k0 = 0; k0 < 512; k0 += 32) {
        if (k0 < 480) {   // issue next tile's DMA BEFORE compute
            const int nb = cur ^ 1, kn = k0 + 32;
            gload16(xb + asrc + kn,        As[nb] + (w * 2 + 0) * 512);
            gload16(xb + asrc + kn + 8192, As[nb] + (w * 2 + 1) * 512);
            gload16(Wz + bsrc + kn,        Bs[nb] + (w * 2 + 0) * 512);
            gload16(Wz + bsrc + kn + 8192, Bs[nb] + (w * 2 + 1) * 512);
        }

        short8 af[4], bfr[4];
#pragma unroll
        for (int i = 0; i < 4; i++)
            af[i] = *(const short8*)(As[cur] + (wm + i * 16 + l15) * 32 + quad * 8);
#pragma unroll
        for (int i = 0; i < 4; i++)
            bfr[i] = *(const short8*)(Bs[cur] + (wn + i * 16 + l15) * 32 + quad * 8);
#pragma unroll
        for (int mi = 0; mi < 4; mi++)
#pragma unroll
            for (int ni = 0; ni < 4; ni++)
                acc[mi][ni] = __builtin_amdgcn_mfma_f32_16x16x32_bf16(
                    af[mi], bfr[ni], acc[mi][ni], 0, 0, 0);

        __syncthreads();   // drains vmcnt (next tile landed) + all reads done
        cur ^= 1;
    }

    if (z < 2) {
        ushortT* Y = (z == 0) ? Qw : Kw;
        const float sc = (z == 0) ? qscale : 1.0f;
#pragma unroll
        for (int ni = 0; ni < 4; ni++) {
            int col = brow0 + wn + ni * 16 + l15;
            float bv_ = bias[col];
#pragma unroll
            for (int mi = 0; mi < 4; mi++)
#pragma unroll
                for (int r = 0; r < 4; r++) {
                    int row = arow0 + wm + mi * 16 + quad * 4 + r;
                    Y[(size_t)row * 512 + col] = f2bf((acc[mi][ni][r] + bv_) * sc);
                }
        }
    } else {
        // V transposed -> Vt[b][ch][seq]
        const int bidx = arow0 >> 12;
        const int s0 = (arow0 & 4095) + wm;
#pragma unroll
        for (int ni = 0; ni < 4; ni++) {
            int ch = brow0 + wn + ni * 16 + l15;
            float bv_ = bias[ch];
            ushortT* vrow = Vtw + (size_t)bidx * 2097152 + (size_t)ch * 4096;
#pragma unroll
            for (int mi = 0; mi < 4; mi++) {
                int s = s0 + mi * 16 + quad * 4;
                unsigned int u0 = cvtpk(acc[mi][ni][0] + bv_, acc[mi][ni][1] + bv_);
                unsigned int u1 = cvtpk(acc[mi][ni][2] + bv_, acc[mi][ni][3] + bv_);
                uint2v st2 = { u0, u1 };
                *(uint2v*)(vrow + s) = st2;
            }
        }
    }
}

// ---------------------------------------------------------------------------
// Final projection, 2-phase dbuf: out[M][512] = O[M][512](bf16) * Wo^T + bo.
// Grid (64,4) x 256 thr. Same schedule as proj_qkv.
// ---------------------------------------------------------------------------
__global__ __launch_bounds__(256) void gemm_out(
    const ushortT* __restrict__ X, const ushortT* __restrict__ Wob,
    const float* __restrict__ bias, float* __restrict__ Y)
{
    __shared__ __align__(16) ushortT As[2][128 * 32];
    __shared__ __align__(16) ushortT Bs[2][128 * 32];
    const int t = threadIdx.x;
    const int w = t >> 6, lane = t & 63;
    const int quad = lane >> 4, l15 = lane & 15;
    const int bm = blockIdx.x * 128, bn = blockIdx.y * 128;
    const int wm = (w >> 1) * 64, wn = (w & 1) * 64;

    const int srow = lane >> 2;
    const int scol = (lane & 3) * 8;
    const size_t asrc = (size_t)(bm + w * 32 + srow) * 512 + scol;
    const size_t bsrc = (size_t)(bn + w * 32 + srow) * 512 + scol;

    f32x4 acc[4][4] = {};

    gload16(X   + asrc,        As[0] + (w * 2 + 0) * 512);
    gload16(X   + asrc + 8192, As[0] + (w * 2 + 1) * 512);
    gload16(Wob + bsrc,        Bs[0] + (w * 2 + 0) * 512);
    gload16(Wob + bsrc + 8192, Bs[0] + (w * 2 + 1) * 512);
    __syncthreads();

    int cur = 0;
    for (int k0 = 0; k0 < 512; k0 += 32) {
        if (k0 < 480) {
            const int nb = cur ^ 1, kn = k0 + 32;
            gload16(X   + asrc + kn,        As[nb] + (w * 2 + 0) * 512);
            gload16(X   + asrc + kn + 8192, As[nb] + (w * 2 + 1) * 512);
            gload16(Wob + bsrc + kn,        Bs[nb] + (w * 2 + 0) * 512);
            gload16(Wob + bsrc + kn + 8192, Bs[nb] + (w * 2 + 1) * 512);
        }

        short8 af[4], bfr[4];
#pragma unroll
        for (int i = 0; i < 4; i++)
            af[i] = *(const short8*)(As[cur] + (wm + i * 16 + l15) * 32 + quad * 8);
#pragma unroll
        for (int i = 0; i < 4; i++)
            bfr[i] = *(const short8*)(Bs[cur] + (wn + i * 16 + l15) * 32 + quad * 8);
#pragma unroll
        for (int mi = 0; mi < 4; mi++)
#pragma unroll
            for (int ni = 0; ni < 4; ni++)
                acc[mi][ni] = __builtin_amdgcn_mfma_f32_16x16x32_bf16(
                    af[mi], bfr[ni], acc[mi][ni], 0, 0, 0);

        __syncthreads();
        cur ^= 1;
    }

#pragma unroll
    for (int ni = 0; ni < 4; ni++) {
        int col = bn + wn + ni * 16 + l15;
        float bv = bias[col];
#pragma unroll
        for (int mi = 0; mi < 4; mi++)
#pragma unroll
            for (int r = 0; r < 4; r++) {
                int row = bm + wm + mi * 16 + quad * 4 + r;
                Y[(size_t)row * 512 + col] = acc[mi][ni][r] + bv;
            }
    }
}

// ---------------------------------------------------------------------------
// p = exp2(s) for a 32x32 S^T-tile; accumulate per-lane row-sum; assemble
// the two PV B-frags (16 k-slots each) via cvt_pk + permlane32_swap.
// ---------------------------------------------------------------------------
__device__ __forceinline__ void softmax_pack(const f32x16 &sacc, float &lp,
                                             uint4v &B0, uint4v &B1)
{
    float p[16];
#pragma unroll
    for (int r = 0; r < 16; r++) {
        p[r] = __builtin_amdgcn_exp2f(sacc[r]);
        lp += p[r];
    }
    unsigned int c00 = cvtpk(p[0],  p[1]),  c01 = cvtpk(p[2],  p[3]);
    unsigned int c10 = cvtpk(p[4],  p[5]),  c11 = cvtpk(p[6],  p[7]);
    unsigned int c20 = cvtpk(p[8],  p[9]),  c21 = cvtpk(p[10], p[11]);
    unsigned int c30 = cvtpk(p[12], p[13]), c31 = cvtpk(p[14], p[15]);
    plswap(c00, c10);   // -> B0.d0, B0.d2   (k-slots 0..15)
    plswap(c01, c11);   // -> B0.d1, B0.d3
    plswap(c20, c30);   // -> B1.d0, B1.d2   (k-slots 16..31)
    plswap(c21, c31);   // -> B1.d1, B1.d3
    B0 = uint4v{ c00, c01, c10, c11 };
    B1 = uint4v{ c20, c21, c30, c31 };
}

// ---------------------------------------------------------------------------
// Flash attention — R8-verified (frozen). XCD-aware swizzle; WQ=64 per wave;
// 8 waves = 2 key-halves x 4 q-waves; double-buffered K/V LDS, ONE barrier
// per k-tile; fp32 LDS combine. Grid (16,16) x 512 thr. Q/O alias.
// ---------------------------------------------------------------------------
__global__ __launch_bounds__(512, 2) void attn(
    const ushortT* Q, const ushortT* __restrict__ K,
    const ushortT* __restrict__ Vt, ushortT* O)
{
    __shared__ __align__(16) ushortT SM[2][2][2][64 * ALDK];   // [K/V][half][buf]

    const int t = threadIdx.x;
    const int w = t >> 6, lane = t & 63;
    const int half = w >> 2, qw = w & 3;
    const int l31 = lane & 31, hh = lane >> 5;

    // XCD-aware swizzle (pure index permutation)
    const int j = blockIdx.x + (blockIdx.y << 4);
    const int qt = (j >> 3) & 15;
    const int bh = ((j & 7) << 1) | (j >> 7);

    const int b = bh >> 3, h = bh & 7;
    const size_t qbase = (size_t)b * 4096 + qt * 256 + qw * 64;

    short8 qf[2][4];
#pragma unroll
    for (int qg = 0; qg < 2; qg++) {
        const ushortT* qp = Q + (qbase + qg * 32 + l31) * 512 + h * 64 + hh * 8;
#pragma unroll
        for (int dk = 0; dk < 4; dk++)
            qf[qg][dk] = *(const short8*)(qp + dk * 16);
    }

    f32x16 oacc[2][2] = {};   // [qg][dt] unnormalized O^T[d][q]
    float lpart[2] = {};      // per-lane row-sum partial per qg

    const int kofs = half * 2048;
    const ushortT* Kbase = K + ((size_t)b * 4096 + kofs) * 512 + h * 64;
    const ushortT* Vbase = Vt + (size_t)b * 2097152 + (size_t)h * 64 * 4096 + kofs;

    const int th = t & 255;
    const int srow = th >> 3, scol = (th & 7) * 8;
    uint4v kg[2], vg[2];

#pragma unroll
    for (int i = 0; i < 2; i++) {
        kg[i] = *(const uint4v*)(Kbase + (size_t)(srow + 32 * i) * 512 + scol);
        vg[i] = *(const uint4v*)(Vbase + (size_t)(srow + 32 * i) * 4096 + scol);
    }
#pragma unroll
    for (int i = 0; i < 2; i++) {
        *(uint4v*)(SM[0][half][0] + (srow + 32 * i) * ALDK + scol) = kg[i];
        *(uint4v*)(SM[1][half][0] + (srow + 32 * i) * ALDK + scol) = vg[i];
    }
    __syncthreads();

    for (int kt = 0; kt < 32; kt++) {
        const int cur = kt & 1;

        if (kt < 31) {
            const int kb = (kt + 1) * 64;
#pragma unroll
            for (int i = 0; i < 2; i++) {
                kg[i] = *(const uint4v*)(Kbase + (size_t)(kb + srow + 32 * i) * 512 + scol);
                vg[i] = *(const uint4v*)(Vbase + (size_t)(srow + 32 * i) * 4096 + kb + scol);
            }
        }

        const ushortT* Kt  = SM[0][half][cur];
        const ushortT* Vtl = SM[1][half][cur];

#pragma unroll
        for (int st = 0; st < 2; st++) {
            short8 kf[4];
#pragma unroll
            for (int dk = 0; dk < 4; dk++)
                kf[dk] = *(const short8*)(Kt + (st * 32 + l31) * ALDK + dk * 16 + hh * 8);
            f32x16 s0 = {}, s1 = {};
#pragma unroll
            for (int dk = 0; dk < 4; dk++) {
                s0 = __builtin_amdgcn_mfma_f32_32x32x16_bf16(kf[dk], qf[0][dk], s0, 0, 0, 0);
                s1 = __builtin_amdgcn_mfma_f32_32x32x16_bf16(kf[dk], qf[1][dk], s1, 0, 0, 0);
            }

            uint4v B00, B01, B10, B11;
            softmax_pack(s0, lpart[0], B00, B01);
            softmax_pack(s1, lpart[1], B10, B11);
            short8 p00 = __builtin_bit_cast(short8, B00);
            short8 p01 = __builtin_bit_cast(short8, B01);
            short8 p10 = __builtin_bit_cast(short8, B10);
            short8 p11 = __builtin_bit_cast(short8, B11);

#pragma unroll
            for (int dt = 0; dt < 2; dt++) {
                short8 vf0 = *(const short8*)(Vtl + (dt * 32 + l31) * ALDK + st * 32 + hh * 8);
                short8 vf1 = *(const short8*)(Vtl + (dt * 32 + l31) * ALDK + st * 32 + 16 + hh * 8);
                oacc[0][dt] = __builtin_amdgcn_mfma_f32_32x32x16_bf16(vf0, p00, oacc[0][dt], 0, 0, 0);
                oacc[0][dt] = __builtin_amdgcn_mfma_f32_32x32x16_bf16(vf1, p01, oacc[0][dt], 0, 0, 0);
                oacc[1][dt] = __builtin_amdgcn_mfma_f32_32x32x16_bf16(vf0, p10, oacc[1][dt], 0, 0, 0);
                oacc[1][dt] = __builtin_amdgcn_mfma_f32_32x32x16_bf16(vf1, p11, oacc[1][dt], 0, 0, 0);
            }
        }

        if (kt < 31) {
            const int nb = cur ^ 1;
#pragma unroll
            for (int i = 0; i < 2; i++) {
                *(uint4v*)(SM[0][half][nb] + (srow + 32 * i) * ALDK + scol) = kg[i];
                *(uint4v*)(SM[1][half][nb] + (srow + 32 * i) * ALDK + scol) = vg[i];
            }
        }
        __syncthreads();
    }

    float* scratch = (float*)&SM[0][0][0][0];
    float* prow = scratch + (size_t)(qw * 64 + lane) * 68;

    if (half == 1) {
#pragma unroll
        for (int qg = 0; qg < 2; qg++)
#pragma unroll
            for (int dt = 0; dt < 2; dt++)
#pragma unroll
                for (int m = 0; m < 4; m++) {
                    f32x4 v4 = { oacc[qg][dt][4 * m + 0], oacc[qg][dt][4 * m + 1],
                                 oacc[qg][dt][4 * m + 2], oacc[qg][dt][4 * m + 3] };
                    *(f32x4*)(prow + qg * 32 + dt * 16 + m * 4) = v4;
                }
        prow[64] = lpart[0];
        prow[65] = lpart[1];
    }
    __syncthreads();

    if (half == 0) {
#pragma unroll
        for (int qg = 0; qg < 2; qg++) {
            float sum = lpart[qg] + prow[64 + qg];
            float l = sum + __shfl_xor(sum, 32);
            float rl = 1.0f / l;

            ushortT* orow = O + (qbase + qg * 32 + l31) * 512 + h * 64 + hh * 4;
#pragma unroll
            for (int dt = 0; dt < 2; dt++)
#pragma unroll
                for (int m = 0; m < 4; m++) {
                    f32x4 v4 = *(const f32x4*)(prow + qg * 32 + dt * 16 + m * 4);
                    unsigned int u0 = cvtpk((oacc[qg][dt][4 * m + 0] + v4[0]) * rl,
                                            (oacc[qg][dt][4 * m + 1] + v4[1]) * rl);
                    unsigned int u1 = cvtpk((oacc[qg][dt][4 * m + 2] + v4[2]) * rl,
                                            (oacc[qg][dt][4 * m + 3] + v4[3]) * rl);
                    uint2v st2 = { u0, u1 };
                    *(uint2v*)(orow + dt * 32 + m * 8) = st2;
                }
        }
    }
}

// ---------------------------------------------------------------------------
extern "C" void kernel_launch(void* const* d_in, const int* in_sizes, int n_in,
                              void* d_out, int out_size, void* d_ws, size_t ws_size,
                              hipStream_t stream)
{
    const float* x  = (const float*)d_in[0];
    const float* Wq = (const float*)d_in[1];
    const float* bq = (const float*)d_in[2];
    const float* Wk = (const float*)d_in[3];
    const float* bk = (const float*)d_in[4];
    const float* Wv = (const float*)d_in[5];
    const float* bv = (const float*)d_in[6];
    const float* Wo = (const float*)d_in[7];
    const float* bo = (const float*)d_in[8];

    ushortT* ws  = (ushortT*)d_ws;
    ushortT* Qw  = ws;                    // 8192*512 bf16 (O in place)
    ushortT* Kw  = ws + 4194304;
    ushortT* Vtw = ws + 8388608;          // 2*512*4096 bf16
    ushortT* xb  = ws + 12582912;         // 8192*512 bf16
    ushortT* wbf = ws + 16777216;         // 4 x 512*512 bf16 (q,k,v,o)

    const float qscale = 0.125f * 1.44269504089f;   // 1/sqrt(64) * log2(e)

    prep<<<dim3(2560), 256, 0, stream>>>(x, Wq, Wk, Wv, Wo, xb, wbf);
    proj_qkv<<<dim3(64, 4, 3), 256, 0, stream>>>(
        xb, wbf, bq, bk, bv, Qw, Kw, Vtw, qscale);
    attn<<<dim3(16, 16), 512, 0, stream>>>(Qw, Kw, Vtw, Qw);
    gemm_out<<<dim3(64, 4), 256, 0, stream>>>(Qw, wbf + 786432, bo, (float*)d_out);
}